// Round 1
// baseline (1326.168 us; speedup 1.0000x reference)
//
#include <hip/hip_runtime.h>

typedef __bf16 bf16x8 __attribute__((ext_vector_type(8)));
typedef float f32x4 __attribute__((ext_vector_type(4)));

__device__ __forceinline__ unsigned short f2bf(float f) {
  union { float f; unsigned u; } v; v.f = f;
  unsigned r = v.u + 0x7fffu + ((v.u >> 16) & 1u);
  return (unsigned short)(r >> 16);
}

__device__ __forceinline__ void gload_lds16(const void* g, void* l) {
  __builtin_amdgcn_global_load_lds(
      (__attribute__((address_space(1))) void*)g,
      (__attribute__((address_space(3))) void*)l, 16, 0, 0);
}

// ---------------- cast fp32 -> bf16, x4 vectorized ----------------
__global__ void cast_kernel(const float* __restrict__ in, unsigned short* __restrict__ out, int n4) {
  int i = blockIdx.x * blockDim.x + threadIdx.x;
  if (i < n4) {
    const float4 v = reinterpret_cast<const float4*>(in)[i];
    ushort4 o;
    o.x = f2bf(v.x); o.y = f2bf(v.y); o.z = f2bf(v.z); o.w = f2bf(v.w);
    reinterpret_cast<ushort4*>(out)[i] = o;
  }
}

// ------------- transpose + cast: in [K][N] f32 -> out [N][K] bf16 -------------
__global__ void transpose_cast_kernel(const float* __restrict__ in, unsigned short* __restrict__ out,
                                      int K, int N) {
  __shared__ float t[32][33];
  int k0 = blockIdx.y * 32, n0 = blockIdx.x * 32;
  int tx = threadIdx.x, ty = threadIdx.y;
  #pragma unroll
  for (int r = ty; r < 32; r += 8) t[r][tx] = in[(size_t)(k0 + r) * N + n0 + tx];
  __syncthreads();
  #pragma unroll
  for (int r = ty; r < 32; r += 8) out[(size_t)(n0 + r) * K + k0 + tx] = f2bf(t[tx][r]);
}

// ---------------- GEMM C = A * Bt^T  (m97 structure, 128x128 tile, BK=32) ----------------
// MODE 0: QKV epilogue -> scatter bf16 into Q/K/V [B,H,S,128]
// MODE 1: fp32 output [M][N]
template<int MODE>
__global__ __launch_bounds__(256) void gemm_bt(
    const unsigned short* __restrict__ A,   // [M][K] bf16
    const unsigned short* __restrict__ Bt,  // [N][K] bf16
    float* __restrict__ outF,
    unsigned short* __restrict__ Qo,
    unsigned short* __restrict__ Ko,
    unsigned short* __restrict__ Vo,
    int M, int N, int K)
{
  __shared__ __align__(16) unsigned short As[128 * 32];
  __shared__ __align__(16) unsigned short Bs[128 * 32];
  const int tid = threadIdx.x;
  const int lane = tid & 63;
  const int w = tid >> 6;
  const int wr = (w >> 1) * 64, wc = (w & 1) * 64;
  const int lr = lane & 15, ls = lane >> 4;
  const int m0 = blockIdx.y * 128, n0 = blockIdx.x * 128;
  f32x4 acc[4][4] = {};
  for (int k0 = 0; k0 < K; k0 += 32) {
    #pragma unroll
    for (int i = 0; i < 2; ++i) {
      int idx = i * 256 + tid;            // [0,512): linear 16B chunks of the 128x32 tile
      int row = idx >> 2, colb = (idx & 3) * 8;
      gload_lds16(A + (size_t)(m0 + row) * K + k0 + colb, &As[idx * 8]);
      gload_lds16(Bt + (size_t)(n0 + row) * K + k0 + colb, &Bs[idx * 8]);
    }
    __syncthreads();
    bf16x8 af[4], bfr[4];
    #pragma unroll
    for (int t = 0; t < 4; ++t) {
      af[t]  = *reinterpret_cast<const bf16x8*>(&As[(wr + t * 16 + lr) * 32 + ls * 8]);
      bfr[t] = *reinterpret_cast<const bf16x8*>(&Bs[(wc + t * 16 + lr) * 32 + ls * 8]);
    }
    #pragma unroll
    for (int mt = 0; mt < 4; ++mt)
      #pragma unroll
      for (int nt = 0; nt < 4; ++nt)
        acc[mt][nt] = __builtin_amdgcn_mfma_f32_16x16x32_bf16(af[mt], bfr[nt], acc[mt][nt], 0, 0, 0);
    __syncthreads();
  }
  #pragma unroll
  for (int mt = 0; mt < 4; ++mt) {
    #pragma unroll
    for (int nt = 0; nt < 4; ++nt) {
      const int n = n0 + wc + nt * 16 + lr;
      #pragma unroll
      for (int r = 0; r < 4; ++r) {
        const int m = m0 + wr + mt * 16 + ls * 4 + r;
        if (MODE == 1) {
          outF[(size_t)m * N + n] = acc[mt][nt][r];
        } else {
          const int b = m >> 11, s = m & 2047;
          const int sec = n >> 11, nn = n & 2047;
          const int h = nn >> 7, d = nn & 127;
          unsigned short* dst = (sec == 0) ? Qo : ((sec == 1) ? Ko : Vo);
          dst[(((size_t)(b * 16 + h) * 2048 + s) << 7) + d] = f2bf(acc[mt][nt][r]);
        }
      }
    }
  }
}

// ---------------- flash attention, causal, 64 q-rows/block, KVBLK=64 ----------------
__global__ __launch_bounds__(256) void attn_kernel(
    const unsigned short* __restrict__ Q,
    const unsigned short* __restrict__ K,
    const unsigned short* __restrict__ V,
    unsigned short* __restrict__ Y)     // [B,S,C] bf16 rows for proj GEMM
{
  __shared__ __align__(16) unsigned short p_lds[4][16][64];
  const int tid = threadIdx.x;
  const int w = tid >> 6, lane = tid & 63;
  const int lr = lane & 15, ls = lane >> 4;
  const int qb = blockIdx.x, h = blockIdx.y, b = blockIdx.z;
  const size_t bh = ((size_t)(b * 16 + h)) << 18;   // * 2048 * 128
  const unsigned short* Qp = Q + bh;
  const unsigned short* Kp = K + bh;
  const unsigned short* Vp = V + bh;
  const int qrow0 = qb * 64 + w * 16;
  bf16x8 qf[4];
  #pragma unroll
  for (int s = 0; s < 4; ++s)
    qf[s] = *reinterpret_cast<const bf16x8*>(&Qp[(size_t)(qrow0 + lr) * 128 + s * 32 + ls * 8]);
  float mrow[4], lrow[4];
  #pragma unroll
  for (int r = 0; r < 4; ++r) { mrow[r] = -__builtin_inff(); lrow[r] = 0.f; }
  f32x4 oacc[8] = {};
  const float scale = 0.088388347648318447f;  // 1/sqrt(128)
  const int kv_end = qb * 64 + 64;
  for (int kv0 = 0; kv0 < kv_end; kv0 += 64) {
    float p[4][4];   // [kv 16-col tile][q row reg]
    #pragma unroll
    for (int t = 0; t < 4; ++t) {
      f32x4 sacc = {};
      #pragma unroll
      for (int s = 0; s < 4; ++s) {
        bf16x8 kf = *reinterpret_cast<const bf16x8*>(
            &Kp[(size_t)(kv0 + t * 16 + lr) * 128 + s * 32 + ls * 8]);
        sacc = __builtin_amdgcn_mfma_f32_16x16x32_bf16(qf[s], kf, sacc, 0, 0, 0);
      }
      const int col = kv0 + t * 16 + lr;
      #pragma unroll
      for (int r = 0; r < 4; ++r) {
        const int row = qrow0 + ls * 4 + r;
        p[t][r] = (col <= row) ? sacc[r] * scale : -__builtin_inff();
      }
    }
    // online softmax (row = ls*4+r, distributed over the 16 lanes of each ls-group)
    #pragma unroll
    for (int r = 0; r < 4; ++r) {
      float mx = fmaxf(fmaxf(p[0][r], p[1][r]), fmaxf(p[2][r], p[3][r]));
      #pragma unroll
      for (int d = 1; d < 16; d <<= 1) mx = fmaxf(mx, __shfl_xor(mx, d));
      const float mnew = fmaxf(mrow[r], mx);
      const float sc = __expf(mrow[r] - mnew);
      float rsum = 0.f;
      #pragma unroll
      for (int t = 0; t < 4; ++t) { float e = __expf(p[t][r] - mnew); p[t][r] = e; rsum += e; }
      #pragma unroll
      for (int d = 1; d < 16; d <<= 1) rsum += __shfl_xor(rsum, d);
      lrow[r] = lrow[r] * sc + rsum;
      mrow[r] = mnew;
      #pragma unroll
      for (int nt = 0; nt < 8; ++nt) oacc[nt][r] *= sc;
    }
    // stage P (bf16) to this wave's LDS region
    #pragma unroll
    for (int t = 0; t < 4; ++t)
      #pragma unroll
      for (int r = 0; r < 4; ++r)
        p_lds[w][ls * 4 + r][t * 16 + lr] = f2bf(p[t][r]);
    __syncthreads();
    // PV: O += P * V
    #pragma unroll
    for (int ks = 0; ks < 2; ++ks) {
      const bf16x8 pf = *reinterpret_cast<const bf16x8*>(&p_lds[w][lr][ks * 32 + ls * 8]);
      const unsigned short* vbase = Vp + (size_t)(kv0 + ks * 32 + ls * 8) * 128 + lr;
      #pragma unroll
      for (int nt = 0; nt < 8; ++nt) {
        bf16x8 vf;
        #pragma unroll
        for (int j = 0; j < 8; ++j)
          reinterpret_cast<unsigned short*>(&vf)[j] = vbase[(size_t)j * 128 + nt * 16];
        oacc[nt] = __builtin_amdgcn_mfma_f32_16x16x32_bf16(pf, vf, oacc[nt], 0, 0, 0);
      }
    }
    __syncthreads();
  }
  // normalize + store Y rows (bf16) at [b, s, h*128 + d]
  const int row = qrow0 + ls * 4;
  #pragma unroll
  for (int r = 0; r < 4; ++r) {
    const float inv = 1.f / lrow[r];
    const size_t rb = ((size_t)b * 2048 + row + r) * 2048 + h * 128 + lr;
    #pragma unroll
    for (int nt = 0; nt < 8; ++nt)
      Y[rb + nt * 16] = f2bf(oacc[nt][r] * inv);
  }
}

extern "C" void kernel_launch(void* const* d_in, const int* in_sizes, int n_in,
                              void* d_out, int out_size, void* d_ws, size_t ws_size,
                              hipStream_t stream) {
  const float* x  = (const float*)d_in[0];   // [4,2048,2048]
  const float* Wa = (const float*)d_in[1];   // [2048,6144]
  const float* Wp = (const float*)d_in[2];   // [2048,2048]
  float* out = (float*)d_out;                // [4,2048,2048] f32

  unsigned short* ws  = (unsigned short*)d_ws;
  unsigned short* xb  = ws;                          // 8192*2048 bf16
  unsigned short* wat = xb  + (size_t)8192 * 2048;   // 6144*2048 bf16 (W_attn^T)
  unsigned short* wpt = wat + (size_t)6144 * 2048;   // 2048*2048 bf16 (W_proj^T)
  unsigned short* Qb  = wpt + (size_t)2048 * 2048;   // [4,16,2048,128] bf16
  unsigned short* Kb  = Qb  + (size_t)4 * 16 * 2048 * 128;
  unsigned short* Vb  = Kb  + (size_t)4 * 16 * 2048 * 128;
  unsigned short* yb  = Vb  + (size_t)4 * 16 * 2048 * 128;  // [4,2048,2048] bf16

  cast_kernel<<<dim3(16384), dim3(256), 0, stream>>>(x, xb, (8192 * 2048) / 4);
  transpose_cast_kernel<<<dim3(192, 64), dim3(32, 8), 0, stream>>>(Wa, wat, 2048, 6144);
  transpose_cast_kernel<<<dim3(64, 64), dim3(32, 8), 0, stream>>>(Wp, wpt, 2048, 2048);

  gemm_bt<0><<<dim3(48, 64), dim3(256), 0, stream>>>(xb, wat, nullptr, Qb, Kb, Vb,
                                                     8192, 6144, 2048);
  attn_kernel<<<dim3(32, 16, 4), dim3(256), 0, stream>>>(Qb, Kb, Vb, yb);
  gemm_bt<1><<<dim3(16, 64), dim3(256), 0, stream>>>(yb, wpt, out, nullptr, nullptr, nullptr,
                                                     8192, 2048, 2048);
}